// Round 1
// baseline (1029.959 us; speedup 1.0000x reference)
//
#include <hip/hip_runtime.h>
#include <hip/hip_bf16.h>

// Problem constants
#define NN 240        // rows (tokens)
#define CC 6144       // channels
#define DD 3072       // head dim
#define C3 18432      // 3*C
#define HH 2          // heads

typedef __attribute__((ext_vector_type(8))) short bf16x8;
typedef __attribute__((ext_vector_type(4))) float f32x4;

static __device__ __forceinline__ unsigned short f2bf(float f) {
    __hip_bfloat16 h = __float2bfloat16(f);
    return __builtin_bit_cast(unsigned short, h);
}

// Stage a 128-row x 64-col fp32 tile (rows are the row-major leading dim,
// K contiguous) into LDS as bf16 with XOR swizzle. Rows >= Rmax are zeroed.
static __device__ __forceinline__ void stage_tile(
    const float* __restrict__ src, int ld, int row0, int Rmax, int k0,
    unsigned short* __restrict__ s) {
    const int tid = threadIdx.x;
#pragma unroll
    for (int u = 0; u < 4; ++u) {           // 1024 16B-chunks / 256 threads
        int c = tid + 256 * u;
        int row = c >> 3, kc = c & 7;       // 8 chunks (64 k) per row
        int grow = row0 + row;
        float4 f0 = make_float4(0.f, 0.f, 0.f, 0.f), f1 = f0;
        if (grow < Rmax) {
            const float* p = src + (size_t)grow * ld + (k0 + kc * 8);
            f0 = *(const float4*)p;
            f1 = *(const float4*)(p + 4);
        }
        int4 w;
        w.x = (int)((unsigned)f2bf(f0.x) | ((unsigned)f2bf(f0.y) << 16));
        w.y = (int)((unsigned)f2bf(f0.z) | ((unsigned)f2bf(f0.w) << 16));
        w.z = (int)((unsigned)f2bf(f1.x) | ((unsigned)f2bf(f1.y) << 16));
        w.w = (int)((unsigned)f2bf(f1.z) | ((unsigned)f2bf(f1.w) << 16));
        // byte offset: row*128 + 16B-slot, slot XOR-swizzled by row&7
        int boff = row * 128 + ((kc * 16) ^ ((row & 7) << 4));
        *reinterpret_cast<int4*>(reinterpret_cast<char*>(s) + boff) = w;
    }
}

// C[M x N] (f32) = A[M x K] * B[N x K]^T  (+ bias), batched over gridDim.z.
// A, B fp32 row-major (K contiguous). 128x128 tile, BK=64, 4 waves of 64x64.
__global__ __launch_bounds__(256)
void gemm_bt(const float* __restrict__ A, int lda, long long sAz,
             const float* __restrict__ B, int ldb, long long sBz,
             const float* __restrict__ bias,
             float* __restrict__ C, int ldc, long long sCz,
             int M, int N, int K) {
    __shared__ unsigned short sA[128 * 64];
    __shared__ unsigned short sB[128 * 64];

    const int z = blockIdx.z;
    A += (size_t)z * sAz;
    B += (size_t)z * sBz;
    C += (size_t)z * sCz;

    const int m0 = blockIdx.y * 128;
    const int n0 = blockIdx.x * 128;
    const int lane = threadIdx.x & 63;
    const int wid  = threadIdx.x >> 6;
    const int wm = wid >> 1, wn = wid & 1;     // 2x2 wave grid
    const int l16 = lane & 15, lk = lane >> 4; // fragment lane decomposition

    f32x4 acc[4][4] = {};

    for (int k0 = 0; k0 < K; k0 += 64) {
        stage_tile(A, lda, m0, M, k0, sA);
        stage_tile(B, ldb, n0, N, k0, sB);
        __syncthreads();
#pragma unroll
        for (int ks = 0; ks < 2; ++ks) {
            bf16x8 af[4], bfr[4];
            const int kcs = (ks * 4 + lk) * 16;  // 16B-slot byte offset for this lane's k
#pragma unroll
            for (int mt = 0; mt < 4; ++mt) {
                int row = wm * 64 + mt * 16 + l16;
                int boff = row * 128 + (kcs ^ ((row & 7) << 4));
                af[mt] = *reinterpret_cast<const bf16x8*>(
                    reinterpret_cast<const char*>(sA) + boff);
            }
#pragma unroll
            for (int nt = 0; nt < 4; ++nt) {
                int row = wn * 64 + nt * 16 + l16;
                int boff = row * 128 + (kcs ^ ((row & 7) << 4));
                bfr[nt] = *reinterpret_cast<const bf16x8*>(
                    reinterpret_cast<const char*>(sB) + boff);
            }
#pragma unroll
            for (int mt = 0; mt < 4; ++mt)
#pragma unroll
                for (int nt = 0; nt < 4; ++nt)
                    acc[mt][nt] = __builtin_amdgcn_mfma_f32_16x16x32_bf16(
                        af[mt], bfr[nt], acc[mt][nt], 0, 0, 0);
        }
        __syncthreads();
    }

    // Epilogue: D row = 4*lk + j, col = l16 within each 16x16 fragment
#pragma unroll
    for (int mt = 0; mt < 4; ++mt) {
#pragma unroll
        for (int j = 0; j < 4; ++j) {
            int grow = m0 + wm * 64 + mt * 16 + lk * 4 + j;
            if (grow < M) {
#pragma unroll
                for (int nt = 0; nt < 4; ++nt) {
                    int gcol = n0 + wn * 64 + nt * 16 + l16;
                    if (gcol < N) {
                        float v = acc[mt][nt][j];
                        if (bias) v += bias[gcol];
                        C[(size_t)grow * ldc + gcol] = v;
                    }
                }
            }
        }
    }
}

// qmax[(h*240+n)*12 + c] = max over q[h][n][c*256 .. c*256+255]
__global__ __launch_bounds__(256)
void qmax_kernel(const float* __restrict__ qkv, float* __restrict__ qmax) {
    int idx = blockIdx.x * 4 + (threadIdx.x >> 6);   // 0..5759
    int lane = threadIdx.x & 63;
    int c = idx % 12;
    int r = idx / 12;            // h*240 + n
    int n = r % NN, h = r / NN;
    const float* p = qkv + (size_t)n * C3 + h * DD + c * 256 + lane * 4;
    float4 f = *(const float4*)p;
    float m = fmaxf(fmaxf(f.x, f.y), fmaxf(f.z, f.w));
#pragma unroll
    for (int off = 32; off >= 1; off >>= 1)
        m = fmaxf(m, __shfl_xor(m, off));
    if (lane == 0) qmax[idx] = m;
}

// In-place row softmax of attn (2*240 rows of 240), applying scale and Pq.
__global__ __launch_bounds__(256)
void softmax_kernel(float* __restrict__ attn, const float* __restrict__ qmax) {
    int r = blockIdx.x * 4 + (threadIdx.x >> 6);   // 0..479 = h*240+n
    int lane = threadIdx.x & 63;
    float* row = attn + (size_t)r * NN;
    const float* qm = qmax + r * 12;
    const float scale = 0.0180421959f;             // 3072^-0.5
    float v[4];
    float mx = -1e30f;
#pragma unroll
    for (int i = 0; i < 4; ++i) {
        int m = lane + 64 * i;
        v[i] = -1e30f;
        if (m < NN) v[i] = row[m] * scale + 0.1f * qm[m % 12];
        mx = fmaxf(mx, v[i]);
    }
#pragma unroll
    for (int off = 32; off >= 1; off >>= 1)
        mx = fmaxf(mx, __shfl_xor(mx, off));
    float s = 0.f;
#pragma unroll
    for (int i = 0; i < 4; ++i) {
        v[i] = __expf(v[i] - mx);   // guarded lanes: exp(-inf) = 0
        s += v[i];
    }
#pragma unroll
    for (int off = 32; off >= 1; off >>= 1)
        s += __shfl_xor(s, off);
    float inv = 1.0f / s;
#pragma unroll
    for (int i = 0; i < 4; ++i) {
        int m = lane + 64 * i;
        if (m < NN) row[m] = v[i] * inv;
    }
}

// pre[n][h*3072+dd] = sum_m attn[h][n][m] * v[h][m][dd]
// grid (12 dd-blocks of 256, 15 n-tiles of 16, 2 heads)
__global__ __launch_bounds__(256)
void pv_kernel(const float* __restrict__ attn, const float* __restrict__ qkv,
               float* __restrict__ pre) {
    const int h = blockIdx.z;
    const int n0 = blockIdx.y * 16;
    const int dd0 = blockIdx.x * 256;
    __shared__ float s_attn[16 * NN];
    for (int i = threadIdx.x; i < 16 * NN; i += 256)
        s_attn[i] = attn[(size_t)h * NN * NN + (n0 + i / NN) * NN + (i % NN)];
    __syncthreads();

    const float* vp = qkv + 2 * CC + h * DD + dd0 + threadIdx.x;
    float acc[16] = {};
    for (int m = 0; m < NN; m += 4) {
        float v0 = vp[(size_t)(m + 0) * C3];
        float v1 = vp[(size_t)(m + 1) * C3];
        float v2 = vp[(size_t)(m + 2) * C3];
        float v3 = vp[(size_t)(m + 3) * C3];
#pragma unroll
        for (int i = 0; i < 16; ++i) {
            float4 a = *(const float4*)&s_attn[i * NN + m];
            acc[i] += a.x * v0 + a.y * v1 + a.z * v2 + a.w * v3;
        }
    }
#pragma unroll
    for (int i = 0; i < 16; ++i)
        pre[(size_t)(n0 + i) * CC + h * DD + dd0 + threadIdx.x] = acc[i];
}

extern "C" void kernel_launch(void* const* d_in, const int* in_sizes, int n_in,
                              void* d_out, int out_size, void* d_ws, size_t ws_size,
                              hipStream_t stream) {
    const float* x      = (const float*)d_in[0];
    const float* w_qkv  = (const float*)d_in[1];
    const float* w_proj = (const float*)d_in[2];
    const float* b_proj = (const float*)d_in[3];
    float* out = (float*)d_out;

    // ws layout (floats): qkv[240*18432] | attn[2*240*240] | qmax[5760] | pre[240*6144]
    float* qkv   = (float*)d_ws;
    float* attn  = qkv + (size_t)NN * C3;
    float* qmaxb = attn + (size_t)HH * NN * NN;
    float* pre   = qmaxb + (size_t)HH * NN * 12;

    // 1. qkv = x @ w_qkv^T   (240 x 18432)
    gemm_bt<<<dim3(C3 / 128, 2, 1), 256, 0, stream>>>(
        x, CC, 0LL, w_qkv, CC, 0LL, nullptr, qkv, C3, 0LL, NN, C3, CC);

    // 2. Pq maxpool over q
    qmax_kernel<<<1440, 256, 0, stream>>>(qkv, qmaxb);

    // 3. attn_raw = Q @ K^T per head (batched over grid.z)
    gemm_bt<<<dim3(2, 2, HH), 256, 0, stream>>>(
        qkv, C3, (long long)DD,            // Q: col offset h*3072
        qkv + CC, C3, (long long)DD,       // K: col offset 6144 + h*3072
        nullptr,
        attn, NN, (long long)NN * NN,
        NN, NN, DD);

    // 4. softmax with scale + 0.1*Pq
    softmax_kernel<<<120, 256, 0, stream>>>(attn, qmaxb);

    // 5. pre = attn @ V  -> (N, C) layout
    pv_kernel<<<dim3(12, 15, HH), 256, 0, stream>>>(attn, qkv, pre);

    // 6. out = pre @ w_proj^T + b_proj
    gemm_bt<<<dim3(CC / 128, 2, 1), 256, 0, stream>>>(
        pre, CC, 0LL, w_proj, CC, 0LL, b_proj, out, CC, 0LL, NN, CC, CC);
}

// Round 2
// 410.862 us; speedup vs baseline: 2.5068x; 2.5068x over previous
//
#include <hip/hip_runtime.h>
#include <hip/hip_bf16.h>

// Problem constants
#define NN 240        // rows (tokens)
#define CC 6144       // channels
#define DD 3072       // head dim
#define C3 18432      // 3*C
#define HH 2          // heads

#define BM 256
#define BN 128
#define BK 64

typedef __attribute__((ext_vector_type(8))) short bf16x8;
typedef __attribute__((ext_vector_type(4))) float f32x4;

static __device__ __forceinline__ unsigned short f2bf(float f) {
    __hip_bfloat16 h = __float2bfloat16(f);
    return __builtin_bit_cast(unsigned short, h);
}

static __device__ __forceinline__ int4 pack8(float4 a, float4 b) {
    int4 w;
    w.x = (int)((unsigned)f2bf(a.x) | ((unsigned)f2bf(a.y) << 16));
    w.y = (int)((unsigned)f2bf(a.z) | ((unsigned)f2bf(a.w) << 16));
    w.z = (int)((unsigned)f2bf(b.x) | ((unsigned)f2bf(b.y) << 16));
    w.w = (int)((unsigned)f2bf(b.z) | ((unsigned)f2bf(b.w) << 16));
    return w;
}

// C_partial[zc][M x N] = A[M x K-chunk] * B[N x K-chunk]^T (+ bias if KS==1 path)
// zc = z*KS + kc. A,B fp32 row-major (K contiguous). 256x128 tile, BK=64,
// 8 waves (4x2) of 64x64. Register-prefetch pipeline, bf16 LDS, XOR swizzle.
__global__ __launch_bounds__(512)
void gemm_bt(const float* __restrict__ A, int lda, long long sAz,
             const float* __restrict__ B, int ldb, long long sBz,
             const float* __restrict__ bias,
             float* __restrict__ C, int ldc, long long sCz,
             int M, int N, int K, int KS) {
    __shared__ unsigned short sA[BM * BK];   // 32 KB
    __shared__ unsigned short sB[BN * BK];   // 16 KB

    const int zc = blockIdx.z;
    const int z  = zc / KS;
    const int kc = zc % KS;
    const int Kc = K / KS;
    const int kb = kc * Kc;
    A += (size_t)z * sAz;
    B += (size_t)z * sBz;
    C += (size_t)zc * sCz;

    const int m0 = blockIdx.y * BM;
    const int n0 = blockIdx.x * BN;
    const int tid  = threadIdx.x;
    const int lane = tid & 63;
    const int wid  = tid >> 6;
    const int wm = wid >> 1, wn = wid & 1;     // 4x2 wave grid, 64x64 per wave
    const int l16 = lane & 15, lk = lane >> 4;

    const int r8 = tid >> 3;     // 0..63
    const int k8 = tid & 7;      // 8-float chunk within BK

    float4 ar[8], br[4];
    const float4 f4z = make_float4(0.f, 0.f, 0.f, 0.f);

    auto LOADT = [&](int t) {
        const float* Ab = A + (size_t)(kb + t * BK) + k8 * 8;
#pragma unroll
        for (int u = 0; u < 4; ++u) {
            int row = r8 + 64 * u;               // 0..255
            float4 a0 = f4z, a1 = f4z;
            if (m0 + row < M) {
                const float* p = Ab + (size_t)(m0 + row) * lda;
                a0 = *(const float4*)p;
                a1 = *(const float4*)(p + 4);
            }
            ar[2 * u] = a0; ar[2 * u + 1] = a1;
        }
        const float* Bb = B + (size_t)(kb + t * BK) + k8 * 8;
#pragma unroll
        for (int u = 0; u < 2; ++u) {
            int row = r8 + 64 * u;               // 0..127
            float4 b0 = f4z, b1 = f4z;
            if (n0 + row < N) {
                const float* p = Bb + (size_t)(n0 + row) * ldb;
                b0 = *(const float4*)p;
                b1 = *(const float4*)(p + 4);
            }
            br[2 * u] = b0; br[2 * u + 1] = b1;
        }
    };

    auto WRITET = [&]() {
#pragma unroll
        for (int u = 0; u < 4; ++u) {
            int row = r8 + 64 * u;
            int boff = row * 128 + ((k8 * 16) ^ ((row & 7) << 4));
            *reinterpret_cast<int4*>(reinterpret_cast<char*>(sA) + boff) =
                pack8(ar[2 * u], ar[2 * u + 1]);
        }
#pragma unroll
        for (int u = 0; u < 2; ++u) {
            int row = r8 + 64 * u;
            int boff = row * 128 + ((k8 * 16) ^ ((row & 7) << 4));
            *reinterpret_cast<int4*>(reinterpret_cast<char*>(sB) + boff) =
                pack8(br[2 * u], br[2 * u + 1]);
        }
    };

    f32x4 acc[4][4] = {};
    const int nt_iters = Kc / BK;

    LOADT(0);
    WRITET();
    __syncthreads();

    for (int t = 0; t < nt_iters; ++t) {
        const bool pf = (t + 1 < nt_iters);
        if (pf) LOADT(t + 1);          // issue next-tile loads (overlap MFMA)
#pragma unroll
        for (int ks = 0; ks < 2; ++ks) {
            const int kcs = (ks * 4 + lk) * 16;
            bf16x8 af[4], bfr[4];
#pragma unroll
            for (int mt = 0; mt < 4; ++mt) {
                int row = wm * 64 + mt * 16 + l16;
                int boff = row * 128 + (kcs ^ ((row & 7) << 4));
                af[mt] = *reinterpret_cast<const bf16x8*>(
                    reinterpret_cast<const char*>(sA) + boff);
            }
#pragma unroll
            for (int nt = 0; nt < 4; ++nt) {
                int row = wn * 64 + nt * 16 + l16;
                int boff = row * 128 + (kcs ^ ((row & 7) << 4));
                bfr[nt] = *reinterpret_cast<const bf16x8*>(
                    reinterpret_cast<const char*>(sB) + boff);
            }
#pragma unroll
            for (int mt = 0; mt < 4; ++mt)
#pragma unroll
                for (int nt = 0; nt < 4; ++nt)
                    acc[mt][nt] = __builtin_amdgcn_mfma_f32_16x16x32_bf16(
                        af[mt], bfr[nt], acc[mt][nt], 0, 0, 0);
        }
        __syncthreads();               // all waves done reading LDS
        if (pf) {
            WRITET();                  // cvt + ds_write next tile
            __syncthreads();
        }
    }

    // Epilogue
#pragma unroll
    for (int mt = 0; mt < 4; ++mt) {
#pragma unroll
        for (int j = 0; j < 4; ++j) {
            int grow = m0 + wm * 64 + mt * 16 + lk * 4 + j;
            if (grow < M) {
#pragma unroll
                for (int nt = 0; nt < 4; ++nt) {
                    int gcol = n0 + wn * 64 + nt * 16 + l16;
                    if (gcol < N) {
                        float v = acc[mt][nt][j];
                        if (bias) v += bias[gcol];
                        C[(size_t)grow * ldc + gcol] = v;
                    }
                }
            }
        }
    }
}

// out[i] = sum_{k<ks} part[k*stride4 + i] (+ bias), float4 granularity
__global__ __launch_bounds__(256)
void reduce_add(const float4* __restrict__ part, long long stride4, int ks,
                const float* __restrict__ bias, int ldc,
                float4* __restrict__ out, int count4) {
    int i = blockIdx.x * 256 + threadIdx.x;
    if (i >= count4) return;
    float4 s = part[i];
    for (int k = 1; k < ks; ++k) {
        float4 p = part[(size_t)k * stride4 + i];
        s.x += p.x; s.y += p.y; s.z += p.z; s.w += p.w;
    }
    if (bias) {
        int col = (i * 4) % ldc;
        s.x += bias[col]; s.y += bias[col + 1];
        s.z += bias[col + 2]; s.w += bias[col + 3];
    }
    out[i] = s;
}

// qmax[(h*240+n)*12 + c] = max over q[h][n][c*256 .. c*256+255]
__global__ __launch_bounds__(256)
void qmax_kernel(const float* __restrict__ qkv, float* __restrict__ qmax) {
    int idx = blockIdx.x * 4 + (threadIdx.x >> 6);   // 0..5759
    int lane = threadIdx.x & 63;
    int c = idx % 12;
    int r = idx / 12;            // h*240 + n
    int n = r % NN, h = r / NN;
    const float* p = qkv + (size_t)n * C3 + h * DD + c * 256 + lane * 4;
    float4 f = *(const float4*)p;
    float m = fmaxf(fmaxf(f.x, f.y), fmaxf(f.z, f.w));
#pragma unroll
    for (int off = 32; off >= 1; off >>= 1)
        m = fmaxf(m, __shfl_xor(m, off));
    if (lane == 0) qmax[idx] = m;
}

// Softmax rows of (scale * sum_kc attp + 0.1*Pq) -> attn
__global__ __launch_bounds__(256)
void softmax_kernel(const float* __restrict__ attp, int ks,
                    float* __restrict__ attn, const float* __restrict__ qmax) {
    int r = blockIdx.x * 4 + (threadIdx.x >> 6);   // 0..479 = h*240+n
    int lane = threadIdx.x & 63;
    int z = r / NN, n = r % NN;
    const float* qm = qmax + r * 12;
    const float scale = 0.0180421959f;             // 3072^-0.5
    float v[4];
    float mx = -1e30f;
#pragma unroll
    for (int i = 0; i < 4; ++i) {
        int m = lane + 64 * i;
        v[i] = -1e30f;
        if (m < NN) {
            float s = 0.f;
            for (int kc = 0; kc < ks; ++kc)
                s += attp[(size_t)(z * ks + kc) * NN * NN + n * NN + m];
            v[i] = s * scale + 0.1f * qm[m % 12];
        }
        mx = fmaxf(mx, v[i]);
    }
#pragma unroll
    for (int off = 32; off >= 1; off >>= 1)
        mx = fmaxf(mx, __shfl_xor(mx, off));
    float s = 0.f;
#pragma unroll
    for (int i = 0; i < 4; ++i) {
        v[i] = __expf(v[i] - mx);
        s += v[i];
    }
#pragma unroll
    for (int off = 32; off >= 1; off >>= 1)
        s += __shfl_xor(s, off);
    float inv = 1.0f / s;
#pragma unroll
    for (int i = 0; i < 4; ++i) {
        int m = lane + 64 * i;
        if (m < NN) attn[(size_t)r * NN + m] = v[i] * inv;
    }
}

// pre[n][h*3072+dd] = sum_m attn[h][n][m] * v[h][m][dd]
__global__ __launch_bounds__(256)
void pv_kernel(const float* __restrict__ attn, const float* __restrict__ qkv,
               float* __restrict__ pre) {
    const int h = blockIdx.z;
    const int n0 = blockIdx.y * 16;
    const int dd0 = blockIdx.x * 256;
    __shared__ float s_attn[16 * NN];
    for (int i = threadIdx.x; i < 16 * NN; i += 256)
        s_attn[i] = attn[(size_t)h * NN * NN + (n0 + i / NN) * NN + (i % NN)];
    __syncthreads();

    const float* vp = qkv + 2 * CC + h * DD + dd0 + threadIdx.x;
    float acc[16] = {};
    for (int m = 0; m < NN; m += 4) {
        float v0 = vp[(size_t)(m + 0) * C3];
        float v1 = vp[(size_t)(m + 1) * C3];
        float v2 = vp[(size_t)(m + 2) * C3];
        float v3 = vp[(size_t)(m + 3) * C3];
#pragma unroll
        for (int i = 0; i < 16; ++i) {
            float4 a = *(const float4*)&s_attn[i * NN + m];
            acc[i] += a.x * v0 + a.y * v1 + a.z * v2 + a.w * v3;
        }
    }
#pragma unroll
    for (int i = 0; i < 16; ++i)
        pre[(size_t)(n0 + i) * CC + h * DD + dd0 + threadIdx.x] = acc[i];
}

extern "C" void kernel_launch(void* const* d_in, const int* in_sizes, int n_in,
                              void* d_out, int out_size, void* d_ws, size_t ws_size,
                              hipStream_t stream) {
    const float* x      = (const float*)d_in[0];
    const float* w_qkv  = (const float*)d_in[1];
    const float* w_proj = (const float*)d_in[2];
    const float* b_proj = (const float*)d_in[3];
    float* out = (float*)d_out;

    // ws layout (floats):
    const size_t f_qkv = (size_t)NN * C3;        // 4,423,680
    const size_t f_attn = (size_t)HH * NN * NN;  //   115,200
    const size_t f_qmax = (size_t)HH * NN * 12;  //     5,760
    const size_t f_pre  = (size_t)NN * CC;       // 1,474,560
    const size_t f_gpart = 2 * f_qkv;            // 8,847,360 (covers 6*f_pre, 48*57600)

    float* qkv   = (float*)d_ws;
    float* attn  = qkv + f_qkv;
    float* qmaxb = attn + f_attn;
    float* pre   = qmaxb + f_qmax;
    float* gpart = pre + f_pre;                  // partials / attp region

    const size_t base = f_qkv + f_attn + f_qmax + f_pre;
    const bool full = ws_size >= (base + f_gpart) * sizeof(float);
    const int KSqkv = full ? 2 : 1;
    const int KSproj = full ? 6 : 1;
    const int KSqk  = full ? 24 : 1;

    // 1. qkv = x @ w_qkv^T   (240 x 18432), K=6144
    if (full) {
        gemm_bt<<<dim3(C3 / BN, 1, KSqkv), 512, 0, stream>>>(
            x, CC, 0LL, w_qkv, CC, 0LL, nullptr,
            gpart, C3, (long long)f_qkv, NN, C3, CC, KSqkv);
        reduce_add<<<(int)(f_qkv / 4 / 256), 256, 0, stream>>>(
            (const float4*)gpart, (long long)(f_qkv / 4), KSqkv,
            nullptr, 0, (float4*)qkv, (int)(f_qkv / 4));
    } else {
        gemm_bt<<<dim3(C3 / BN, 1, 1), 512, 0, stream>>>(
            x, CC, 0LL, w_qkv, CC, 0LL, nullptr,
            qkv, C3, 0LL, NN, C3, CC, 1);
    }

    // 2. Pq maxpool over q
    qmax_kernel<<<1440, 256, 0, stream>>>(qkv, qmaxb);

    // 3. attn_raw partials = Q @ K^T per head, split-K
    gemm_bt<<<dim3(2, 1, HH * KSqk), 512, 0, stream>>>(
        qkv, C3, (long long)DD,
        qkv + CC, C3, (long long)DD,
        nullptr,
        gpart, NN, (long long)NN * NN,
        NN, NN, DD, KSqk);

    // 4. softmax (fuses split-K reduce, scale, +0.1*Pq)
    softmax_kernel<<<120, 256, 0, stream>>>(gpart, KSqk, attn, qmaxb);

    // 5. pre = attn @ V  -> (N, C) layout
    pv_kernel<<<dim3(12, 15, HH), 256, 0, stream>>>(attn, qkv, pre);

    // 6. out = pre @ w_proj^T + b_proj, K=6144
    if (full) {
        gemm_bt<<<dim3(CC / BN, 1, KSproj), 512, 0, stream>>>(
            pre, CC, 0LL, w_proj, CC, 0LL, nullptr,
            gpart, CC, (long long)f_pre, NN, CC, CC, KSproj);
        reduce_add<<<(int)(f_pre / 4 / 256), 256, 0, stream>>>(
            (const float4*)gpart, (long long)(f_pre / 4), KSproj,
            b_proj, CC, (float4*)out, (int)(f_pre / 4));
    } else {
        gemm_bt<<<dim3(CC / BN, 1, 1), 512, 0, stream>>>(
            pre, CC, 0LL, w_proj, CC, 0LL, b_proj,
            out, CC, 0LL, NN, CC, CC, 1);
    }
}